// Round 1
// baseline (83.146 us; speedup 1.0000x reference)
//
#include <hip/hip_runtime.h>

#define NUM_TGT 5

// Lexicographic (cost, index) compare — replicates lax.top_k stability
// (ascending cost, ascending index on ties).
__device__ __forceinline__ bool lex_less(float c1, int q1, float c2, int q2) {
    return (c1 < c2) || (c1 == c2 && q1 < q2);
}

// Insert (cv,qv) into sorted-ascending 5-list held in registers (static idx only).
__device__ __forceinline__ void insert5(float c[5], int q[5], float cv, int qv) {
    if (lex_less(cv, qv, c[4], q[4])) {
        c[4] = cv; q[4] = qv;
#pragma unroll
        for (int i = 3; i >= 0; --i) {
            if (lex_less(c[i + 1], q[i + 1], c[i], q[i])) {
                float tc = c[i]; c[i] = c[i + 1]; c[i + 1] = tc;
                int   tq = q[i]; q[i] = q[i + 1]; q[i + 1] = tq;
            }
        }
    }
}

// ---------------------------------------------------------------------------
// Fused kernel: one block per batch, 320 threads = 5 waves.
// Wave w owns target w: computes the per-target top-5 (cost, query) list via
// per-lane insertion over a strided query range + 6-step butterfly merge.
// Lists land in LDS; then all 5 waves enumerate the 5^5 candidate tuples,
// lexicographic argmin on (total, candidate-index), decode, argsort rows,
// write output. One launch, no global intermediate.
// ---------------------------------------------------------------------------
__global__ __launch_bounds__(320)
void fused_matcher_kernel(const float* __restrict__ pred_regs,  // [bs][nq][3]
                          const float* __restrict__ tgt_reg,    // [bs*5][3]
                          int* __restrict__ out,                // rows[bs][5] ++ cols[bs][5]
                          int bs, int nq) {
    const int b    = blockIdx.x;
    const int tid  = threadIdx.x;
    const int wave = tid >> 6;            // 0..4 == target index
    const int lane = tid & 63;

    __shared__ float top_c[NUM_TGT][NUM_TGT];
    __shared__ int   top_q[NUM_TGT][NUM_TGT];
    __shared__ float red_t[NUM_TGT];
    __shared__ int   red_k[NUM_TGT];

    // ---- Phase 1: per-wave top-5 for target `wave` ----
    const int bt = b * NUM_TGT + wave;
    const float t0 = tgt_reg[bt * 3 + 0];
    const float t1 = tgt_reg[bt * 3 + 1];
    const float t2 = tgt_reg[bt * 3 + 2];

    float c[5] = {INFINITY, INFINITY, INFINITY, INFINITY, INFINITY};
    int   q[5] = {0x7fffffff, 0x7fffffff, 0x7fffffff, 0x7fffffff, 0x7fffffff};

    const float* base = pred_regs + (size_t)b * nq * 3;
    for (int qi = lane; qi < nq; qi += 64) {
        // fp32 sum order matches jnp.sum over last axis: (|d0|+|d1|)+|d2|
        float cost = fabsf(base[qi * 3 + 0] - t0);
        cost = cost + fabsf(base[qi * 3 + 1] - t1);
        cost = cost + fabsf(base[qi * 3 + 2] - t2);
        cost = cost + 1.0f;   // COST_REG*cost_reg + COST_CLASS
        insert5(c, q, cost, qi);
    }

    // Butterfly merge across the wave: after 6 steps every lane holds the
    // wave-global top-5 (keys (cost,idx) are distinct by idx, so all lanes
    // converge to the identical list).
#pragma unroll
    for (int m = 1; m < 64; m <<= 1) {
#pragma unroll
        for (int i = 0; i < 5; ++i) {
            float oc = __shfl_xor(c[i], m, 64);
            int   oq = __shfl_xor(q[i], m, 64);
            insert5(c, q, oc, oq);
        }
    }

    if (lane == 0) {
#pragma unroll
        for (int i = 0; i < 5; ++i) { top_c[wave][i] = c[i]; top_q[wave][i] = q[i]; }
    }
    __syncthreads();

    // ---- Phase 2: enumerate 5^5 tuples across all 320 threads ----
    float bcost = INFINITY;
    int   bk    = 0x7fffffff;
    for (int k = tid; k < 3125; k += 320) {
        int r  = k;
        const int d0 = r / 625; r -= d0 * 625;
        const int d1 = r / 125; r -= d1 * 125;
        const int d2 = r / 25;  r -= d2 * 25;
        const int d3 = r / 5;
        const int d4 = r - d3 * 5;

        const int q0 = top_q[0][d0], q1 = top_q[1][d1], q2 = top_q[2][d2],
                  q3 = top_q[3][d3], q4 = top_q[4][d4];
        const bool valid =
            q0 != q1 && q0 != q2 && q0 != q3 && q0 != q4 &&
            q1 != q2 && q1 != q3 && q1 != q4 &&
            q2 != q3 && q2 != q4 &&
            q3 != q4;

        // total summed t=0..4 sequentially, matching cand_c.sum(-1)
        float tot = top_c[0][d0];
        tot = tot + top_c[1][d1];
        tot = tot + top_c[2][d2];
        tot = tot + top_c[3][d3];
        tot = tot + top_c[4][d4];
        if (!valid) tot = INFINITY;

        if (tot < bcost || (tot == bcost && k < bk)) { bcost = tot; bk = k; }
    }

    // wave-level lexicographic min-reduce
#pragma unroll
    for (int off = 32; off; off >>= 1) {
        float ot = __shfl_down(bcost, off, 64);
        int   ok = __shfl_down(bk, off, 64);
        if (ot < bcost || (ot == bcost && ok < bk)) { bcost = ot; bk = ok; }
    }
    if (lane == 0) { red_t[wave] = bcost; red_k[wave] = bk; }
    __syncthreads();

    if (tid == 0) {
        float fbt = red_t[0]; int fbk = red_k[0];
#pragma unroll
        for (int w = 1; w < NUM_TGT; ++w) {
            if (red_t[w] < fbt || (red_t[w] == fbt && red_k[w] < fbk)) {
                fbt = red_t[w]; fbk = red_k[w];
            }
        }
        int r = fbk;
        int d[5];
        d[0] = r / 625; r -= d[0] * 625;
        d[1] = r / 125; r -= d[1] * 125;
        d[2] = r / 25;  r -= d[2] * 25;
        d[3] = r / 5;
        d[4] = r - d[3] * 5;

        int rows[5];
#pragma unroll
        for (int t = 0; t < 5; ++t) rows[t] = top_q[t][d[t]];

        // order = argsort(rows); rows are distinct for a valid tuple.
#pragma unroll
        for (int i = 0; i < 5; ++i) {
            int rank = 0;
#pragma unroll
            for (int j = 0; j < 5; ++j) rank += (rows[j] < rows[i]);
            out[b * 5 + rank]          = rows[i];
            out[bs * 5 + b * 5 + rank] = i;
        }
    }
}

extern "C" void kernel_launch(void* const* d_in, const int* in_sizes, int n_in,
                              void* d_out, int out_size, void* d_ws, size_t ws_size,
                              hipStream_t stream) {
    // inputs: [0] pred_logits (bs*nq) fp32 (UNUSED), [1] pred_regs (bs*nq*3) fp32,
    //         [2] labels (bs*5) int32 (UNUSED), [3] tgt_regression (bs*5*3) fp32
    const float* pred_regs = (const float*)d_in[1];
    const float* tgt_reg   = (const float*)d_in[3];
    int* out = (int*)d_out;

    const int T  = in_sizes[2];       // bs * NUM_TGT
    const int bs = T / NUM_TGT;
    const int nq = in_sizes[0] / bs;  // pred_logits is (bs, nq, 1)

    fused_matcher_kernel<<<bs, 64 * NUM_TGT, 0, stream>>>(pred_regs, tgt_reg, out, bs, nq);
}

// Round 2
// 76.284 us; speedup vs baseline: 1.0900x; 1.0900x over previous
//
#include <hip/hip_runtime.h>

#define NUM_TGT 5
#define NWAVES  16   // 1024 threads
#define NACT    15   // active phase-1 waves: 5 targets x 3 slices
#define MAXJ    11   // prefetch depth: covers nq <= 11*192 = 2112

// Lexicographic (cost, index) compare — replicates lax.top_k stability
// (ascending cost, ascending index on ties).
__device__ __forceinline__ bool lex_less(float c1, int q1, float c2, int q2) {
    return (c1 < c2) || (c1 == c2 && q1 < q2);
}

// Insert (cv,qv) into sorted-ascending 5-list held in registers (static idx only).
__device__ __forceinline__ void insert5(float c[5], int q[5], float cv, int qv) {
    if (lex_less(cv, qv, c[4], q[4])) {
        c[4] = cv; q[4] = qv;
#pragma unroll
        for (int i = 3; i >= 0; --i) {
            if (lex_less(c[i + 1], q[i + 1], c[i], q[i])) {
                float tc = c[i]; c[i] = c[i + 1]; c[i + 1] = tc;
                int   tq = q[i]; q[i] = q[i + 1]; q[i + 1] = tq;
            }
        }
    }
}

// ---------------------------------------------------------------------------
// Fused kernel: one block per batch, 1024 threads = 16 waves.
// Phase 1: waves 0..14 cover (target = w/3, query-slice = w%3); each lane
//   prefetches all its ~11 query rows into registers (independent loads, one
//   latency), then runs the register-only insert chain, then a 6-step
//   butterfly merge -> per-(target,slice) top-5 in LDS.
// Merge: threads 0..4 fold the 3 slice-lists of their target (15 inserts).
// Phase 2: all 1024 threads enumerate the 5^5 tuples (<=4 each),
//   lexicographic argmin on (total, tuple-index), decode, argsort rows,
//   write output. One launch, no global intermediate.
// ---------------------------------------------------------------------------
__global__ __launch_bounds__(1024)
void fused_matcher_kernel(const float* __restrict__ pred_regs,  // [bs][nq][3]
                          const float* __restrict__ tgt_reg,    // [bs*5][3]
                          int* __restrict__ out,                // rows[bs][5] ++ cols[bs][5]
                          int bs, int nq) {
    const int b    = blockIdx.x;
    const int tid  = threadIdx.x;
    const int wave = tid >> 6;
    const int lane = tid & 63;

    __shared__ float cand_c[NACT][NUM_TGT];
    __shared__ int   cand_q[NACT][NUM_TGT];
    __shared__ float top_c[NUM_TGT][NUM_TGT];
    __shared__ int   top_q[NUM_TGT][NUM_TGT];
    __shared__ float red_t[NWAVES];
    __shared__ int   red_k[NWAVES];

    // ---- Phase 1: per-(target,slice) top-5 ----
    const bool act   = (wave < NACT);
    const int  t     = wave / 3;        // target 0..4 (junk for wave 15, unused)
    const int  slice = wave - t * 3;    // 0..2

    float t0 = 0.f, t1 = 0.f, t2 = 0.f;
    if (act) {
        const int bt = b * NUM_TGT + t;
        t0 = tgt_reg[bt * 3 + 0];
        t1 = tgt_reg[bt * 3 + 1];
        t2 = tgt_reg[bt * 3 + 2];
    }

    float c[5] = {INFINITY, INFINITY, INFINITY, INFINITY, INFINITY};
    int   q[5] = {0x7fffffff, 0x7fffffff, 0x7fffffff, 0x7fffffff, 0x7fffffff};

    const float* base = pred_regs + (size_t)b * nq * 3;

    // Prefetch: all loads independent -> single memory-latency exposure.
    float v0[MAXJ], v1[MAXJ], v2[MAXJ];
    int   qx[MAXJ];
#pragma unroll
    for (int j = 0; j < MAXJ; ++j) {
        const int qi = slice * 64 + lane + j * 192;
        const bool ok = act && (qi < nq);
        qx[j] = ok ? qi : -1;
        if (ok) {
            v0[j] = base[qi * 3 + 0];
            v1[j] = base[qi * 3 + 1];
            v2[j] = base[qi * 3 + 2];
        }
    }
    // Register-only insert chain (ascending qi order per lane -> tie order ok).
#pragma unroll
    for (int j = 0; j < MAXJ; ++j) {
        if (qx[j] >= 0) {
            // fp32 sum order matches jnp.sum over last axis: (|d0|+|d1|)+|d2|
            float cost = fabsf(v0[j] - t0);
            cost = cost + fabsf(v1[j] - t1);
            cost = cost + fabsf(v2[j] - t2);
            cost = cost + 1.0f;   // COST_REG*cost_reg + COST_CLASS
            insert5(c, q, cost, qx[j]);
        }
    }
    // Generic tail for nq > MAXJ*192 (not taken at nq=2048).
    if (act) {
        for (int qi = slice * 64 + lane + MAXJ * 192; qi < nq; qi += 192) {
            float cost = fabsf(base[qi * 3 + 0] - t0);
            cost = cost + fabsf(base[qi * 3 + 1] - t1);
            cost = cost + fabsf(base[qi * 3 + 2] - t2);
            cost = cost + 1.0f;
            insert5(c, q, cost, qi);
        }
    }

    // Butterfly merge across the wave: after 6 steps every lane holds the
    // wave-global top-5 (keys (cost,idx) distinct by idx -> all lanes converge).
#pragma unroll
    for (int m = 1; m < 64; m <<= 1) {
#pragma unroll
        for (int i = 0; i < 5; ++i) {
            float oc = __shfl_xor(c[i], m, 64);
            int   oq = __shfl_xor(q[i], m, 64);
            insert5(c, q, oc, oq);
        }
    }

    if (act && lane == 0) {
#pragma unroll
        for (int i = 0; i < 5; ++i) { cand_c[wave][i] = c[i]; cand_q[wave][i] = q[i]; }
    }
    __syncthreads();

    // ---- Merge the 3 slice-lists per target (threads 0..4) ----
    if (tid < NUM_TGT) {
        float mc[5]; int mq[5];
#pragma unroll
        for (int i = 0; i < 5; ++i) { mc[i] = cand_c[tid * 3][i]; mq[i] = cand_q[tid * 3][i]; }
#pragma unroll
        for (int s = 1; s < 3; ++s)
#pragma unroll
            for (int i = 0; i < 5; ++i)
                insert5(mc, mq, cand_c[tid * 3 + s][i], cand_q[tid * 3 + s][i]);
#pragma unroll
        for (int i = 0; i < 5; ++i) { top_c[tid][i] = mc[i]; top_q[tid][i] = mq[i]; }
    }
    __syncthreads();

    // ---- Phase 2: enumerate 5^5 tuples across all 1024 threads ----
    float bcost = INFINITY;
    int   bk    = 0x7fffffff;
    for (int k = tid; k < 3125; k += 1024) {
        int r  = k;
        const int d0 = r / 625; r -= d0 * 625;
        const int d1 = r / 125; r -= d1 * 125;
        const int d2 = r / 25;  r -= d2 * 25;
        const int d3 = r / 5;
        const int d4 = r - d3 * 5;

        const int q0 = top_q[0][d0], q1 = top_q[1][d1], q2 = top_q[2][d2],
                  q3 = top_q[3][d3], q4 = top_q[4][d4];
        const bool valid =
            q0 != q1 && q0 != q2 && q0 != q3 && q0 != q4 &&
            q1 != q2 && q1 != q3 && q1 != q4 &&
            q2 != q3 && q2 != q4 &&
            q3 != q4;

        // total summed t=0..4 sequentially, matching cand_c.sum(-1)
        float tot = top_c[0][d0];
        tot = tot + top_c[1][d1];
        tot = tot + top_c[2][d2];
        tot = tot + top_c[3][d3];
        tot = tot + top_c[4][d4];
        if (!valid) tot = INFINITY;

        if (tot < bcost || (tot == bcost && k < bk)) { bcost = tot; bk = k; }
    }

    // wave-level lexicographic min-reduce
#pragma unroll
    for (int off = 32; off; off >>= 1) {
        float ot = __shfl_down(bcost, off, 64);
        int   ok = __shfl_down(bk, off, 64);
        if (ot < bcost || (ot == bcost && ok < bk)) { bcost = ot; bk = ok; }
    }
    if (lane == 0) { red_t[wave] = bcost; red_k[wave] = bk; }
    __syncthreads();

    if (tid == 0) {
        float fbt = red_t[0]; int fbk = red_k[0];
#pragma unroll
        for (int w = 1; w < NWAVES; ++w) {
            if (red_t[w] < fbt || (red_t[w] == fbt && red_k[w] < fbk)) {
                fbt = red_t[w]; fbk = red_k[w];
            }
        }
        int r = fbk;
        int d[5];
        d[0] = r / 625; r -= d[0] * 625;
        d[1] = r / 125; r -= d[1] * 125;
        d[2] = r / 25;  r -= d[2] * 25;
        d[3] = r / 5;
        d[4] = r - d[3] * 5;

        int rows[5];
#pragma unroll
        for (int t2i = 0; t2i < 5; ++t2i) rows[t2i] = top_q[t2i][d[t2i]];

        // order = argsort(rows); rows are distinct for a valid tuple.
#pragma unroll
        for (int i = 0; i < 5; ++i) {
            int rank = 0;
#pragma unroll
            for (int j = 0; j < 5; ++j) rank += (rows[j] < rows[i]);
            out[b * 5 + rank]          = rows[i];
            out[bs * 5 + b * 5 + rank] = i;
        }
    }
}

extern "C" void kernel_launch(void* const* d_in, const int* in_sizes, int n_in,
                              void* d_out, int out_size, void* d_ws, size_t ws_size,
                              hipStream_t stream) {
    // inputs: [0] pred_logits (bs*nq) fp32 (UNUSED), [1] pred_regs (bs*nq*3) fp32,
    //         [2] labels (bs*5) int32 (UNUSED), [3] tgt_regression (bs*5*3) fp32
    const float* pred_regs = (const float*)d_in[1];
    const float* tgt_reg   = (const float*)d_in[3];
    int* out = (int*)d_out;

    const int T  = in_sizes[2];       // bs * NUM_TGT
    const int bs = T / NUM_TGT;
    const int nq = in_sizes[0] / bs;  // pred_logits is (bs, nq, 1)

    fused_matcher_kernel<<<bs, 1024, 0, stream>>>(pred_regs, tgt_reg, out, bs, nq);
}